// Round 5
// baseline (362.389 us; speedup 1.0000x reference)
//
#include <hip/hip_runtime.h>
#include <hip/hip_bf16.h>
#include <stdint.h>

typedef __attribute__((ext_vector_type(8))) short short8;
typedef __attribute__((ext_vector_type(4))) float floatx4;

// ---------------- db4 filter constants ----------------
__device__ __constant__ float c_DL[8] = {
    -0.010597401784997278f, 0.032883011666982945f, 0.030841381835986965f,
    -0.18703481171888114f, -0.02798376941698385f, 0.6308807679295904f,
    0.7148465705525415f, 0.23037781330885523f};
__device__ __constant__ float c_DH[8] = {
    -0.23037781330885523f, 0.7148465705525415f, -0.6308807679295904f,
    -0.02798376941698385f, 0.18703481171888114f, 0.030841381835986965f,
    -0.032883011666982945f, -0.010597401784997278f};
// REC_LO = reverse(DEC_LO) (also used as reversed-order analysis lowpass)
__device__ __constant__ float c_RL[8] = {
    0.23037781330885523f, 0.7148465705525415f, 0.6308807679295904f,
    -0.02798376941698385f, -0.18703481171888114f, 0.030841381835986965f,
    0.032883011666982945f, -0.010597401784997278f};
__device__ __constant__ float c_RH[8] = {
    -0.010597401784997278f, -0.032883011666982945f, 0.030841381835986965f,
    0.18703481171888114f, -0.02798376941698385f, -0.6308807679295904f,
    0.7148465705525415f, -0.23037781330885523f};

__device__ __forceinline__ float bflo(uint32_t u) { return __uint_as_float(u << 16); }
__device__ __forceinline__ float bfhi(uint32_t u) { return __uint_as_float(u & 0xffff0000u); }
__device__ __forceinline__ float ldf(const float* p, size_t i) { return p[i]; }
__device__ __forceinline__ float ldf(const __hip_bfloat16* p, size_t i) { return __bfloat162float(p[i]); }
__device__ __forceinline__ void stf(float* p, size_t i, float v) { p[i] = v; }
__device__ __forceinline__ void stf(__hip_bfloat16* p, size_t i, float v) { p[i] = __float2bfloat16(v); }
__device__ __forceinline__ short f2bs(float f) {
  __hip_bfloat16 h = __float2bfloat16(f);
  return *reinterpret_cast<short*>(&h);
}

__device__ __forceinline__ int reflect_idx(int t, int n) {
  if (t < 0) t = -1 - t;
  if (t >= n) t = 2 * n - 1 - t;
  return t;
}

// Row strides (padded for aligned vector access)
#define S1R 4100
#define S2R 2056

// ---------------- Level-1 DWT: x (B,N,C) fp32, transposed read -> a1,d1 (B*C, stride 4100) bf16
#define NT1 134
__global__ __launch_bounds__(256) void k_dwt_first(const float* __restrict__ x,
                                                   __hip_bfloat16* __restrict__ outa,
                                                   __hip_bfloat16* __restrict__ outd) {
  const int b = blockIdx.y;
  const int k0 = blockIdx.x * 64;
  const int tid = threadIdx.x;
  __shared__ float xs[NT1 * 65];

  const float4* x4 = (const float4*)x;
  for (int idx = tid; idx < NT1 * 16; idx += 256) {
    int nl = idx >> 4, cq = idx & 15;
    int t = 2 * k0 - 6 + nl;
    int n = reflect_idx(t, 8192);
    float4 v = x4[((size_t)b * 8192 + n) * 16 + cq];
    float* d = &xs[nl * 65 + 4 * cq];
    d[0] = v.x; d[1] = v.y; d[2] = v.z; d[3] = v.w;
  }
  __syncthreads();

  const int kk = tid & 63;
  const int k = k0 + kk;
  if (k >= 4099) return;
  for (int c = (tid >> 6); c < 64; c += 4) {
    float lo = 0.f, hi = 0.f;
#pragma unroll
    for (int j = 0; j < 8; ++j) {
      float v = xs[(2 * kk + 7 - j) * 65 + c];
      lo += c_DL[j] * v;
      hi += c_DH[j] * v;
    }
    size_t s = (size_t)b * 64 + c;
    outa[s * S1R + k] = __float2bfloat16(lo);
    outd[s * S1R + k] = __float2bfloat16(hi);
  }
}

// ---------------- Fused analysis levels 2..4, one row per block
__global__ __launch_bounds__(256) void k_ana234(const __hip_bfloat16* __restrict__ a1,
                                                __hip_bfloat16* __restrict__ d2o,
                                                float* __restrict__ d3o,
                                                float* __restrict__ a4o,
                                                float* __restrict__ d4o) {
  const int r = blockIdx.x;
  const int tid = threadIdx.x;
  __shared__ float s1[4100];
  __shared__ float s2[2054];
  __shared__ float s3[1032];

  const uint2* row2 = (const uint2*)(a1 + (size_t)r * S1R);
  for (int i = tid; i < 1025; i += 256) {
    uint2 u = row2[i];
    int e = 4 * i;
    s1[e] = bflo(u.x); s1[e + 1] = bfhi(u.x);
    s1[e + 2] = bflo(u.y); s1[e + 3] = bfhi(u.y);
  }
  __syncthreads();

  // level 2: n=4099 -> m=2053
  for (int k = tid; k < 2053; k += 256) {
    float lo = 0.f, hi = 0.f;
    if (k >= 3 && k <= 2048) {
      const float2* p = (const float2*)&s1[2 * k - 6];
      float2 v0 = p[0], v1 = p[1], v2 = p[2], v3 = p[3];
      lo = c_RL[0]*v0.x + c_RL[1]*v0.y + c_RL[2]*v1.x + c_RL[3]*v1.y +
           c_RL[4]*v2.x + c_RL[5]*v2.y + c_RL[6]*v3.x + c_RL[7]*v3.y;
      hi = c_RH[0]*v0.x + c_RH[1]*v0.y + c_RH[2]*v1.x + c_RH[3]*v1.y +
           c_RH[4]*v2.x + c_RH[5]*v2.y + c_RH[6]*v3.x + c_RH[7]*v3.y;
    } else {
#pragma unroll
      for (int j = 0; j < 8; ++j) {
        float v = s1[reflect_idx(2 * k + 1 - j, 4099)];
        lo += c_DL[j] * v; hi += c_DH[j] * v;
      }
    }
    d2o[(size_t)r * S2R + k] = __float2bfloat16(hi);
    s2[k] = lo;
  }
  __syncthreads();

  // level 3: n=2053 -> m=1030
  for (int k = tid; k < 1030; k += 256) {
    float lo = 0.f, hi = 0.f;
    if (k >= 3 && k <= 1025) {
      const float2* p = (const float2*)&s2[2 * k - 6];
      float2 v0 = p[0], v1 = p[1], v2 = p[2], v3 = p[3];
      lo = c_RL[0]*v0.x + c_RL[1]*v0.y + c_RL[2]*v1.x + c_RL[3]*v1.y +
           c_RL[4]*v2.x + c_RL[5]*v2.y + c_RL[6]*v3.x + c_RL[7]*v3.y;
      hi = c_RH[0]*v0.x + c_RH[1]*v0.y + c_RH[2]*v1.x + c_RH[3]*v1.y +
           c_RH[4]*v2.x + c_RH[5]*v2.y + c_RH[6]*v3.x + c_RH[7]*v3.y;
    } else {
#pragma unroll
      for (int j = 0; j < 8; ++j) {
        float v = s2[reflect_idx(2 * k + 1 - j, 2053)];
        lo += c_DL[j] * v; hi += c_DH[j] * v;
      }
    }
    d3o[(size_t)r * 1030 + k] = hi;
    s3[k] = lo;
  }
  __syncthreads();

  // level 4: n=1030 -> m=518
  for (int k = tid; k < 518; k += 256) {
    float lo = 0.f, hi = 0.f;
    if (k >= 3 && k <= 514) {
      const float2* p = (const float2*)&s3[2 * k - 6];
      float2 v0 = p[0], v1 = p[1], v2 = p[2], v3 = p[3];
      lo = c_RL[0]*v0.x + c_RL[1]*v0.y + c_RL[2]*v1.x + c_RL[3]*v1.y +
           c_RL[4]*v2.x + c_RL[5]*v2.y + c_RL[6]*v3.x + c_RL[7]*v3.y;
      hi = c_RH[0]*v0.x + c_RH[1]*v0.y + c_RH[2]*v1.x + c_RH[3]*v1.y +
           c_RH[4]*v2.x + c_RH[5]*v2.y + c_RH[6]*v3.x + c_RH[7]*v3.y;
    } else {
#pragma unroll
      for (int j = 0; j < 8; ++j) {
        float v = s3[reflect_idx(2 * k + 1 - j, 1030)];
        lo += c_DL[j] * v; hi += c_DH[j] * v;
      }
    }
    a4o[(size_t)r * 518 + k] = lo;
    d4o[(size_t)r * 518 + k] = hi;
  }
}

// ---------------- Channel mixing: 8 batches register-blocked per thread
// grid (130, 4): blockIdx.y = batch-group of 8. Each w element loaded once per group.
__global__ __launch_bounds__(256) void k_mix(const float* __restrict__ a4,
                                             const float* __restrict__ d4,
                                             const float* __restrict__ w1,
                                             const float* __restrict__ w2,
                                             float* __restrict__ am,
                                             float* __restrict__ dm) {
  int idx = blockIdx.x * 256 + threadIdx.x;
  if (idx >= 64 * 518) return;
  int o = idx / 518;
  int p = idx - o * 518;
  int b0 = blockIdx.y * 8;

  float accA[8], accD[8];
#pragma unroll
  for (int j = 0; j < 8; ++j) { accA[j] = 0.f; accD[j] = 0.f; }

  const float* w1p = w1 + (size_t)o * 518 + p;            // + i*64*518
  const float* w2p = w2 + (size_t)o * 518 + p;
  const float* a4p = a4 + (size_t)b0 * 64 * 518 + p;      // + (j*64+i)*518
  const float* d4p = d4 + (size_t)b0 * 64 * 518 + p;

  for (int i = 0; i < 64; ++i) {
    float wa = w1p[(size_t)i * (64 * 518)];
    float wd = w2p[(size_t)i * (64 * 518)];
#pragma unroll
    for (int j = 0; j < 8; ++j) {
      size_t off = (size_t)(j * 64 + i) * 518;
      accA[j] += a4p[off] * wa;
      accD[j] += d4p[off] * wd;
    }
  }
#pragma unroll
  for (int j = 0; j < 8; ++j) {
    size_t off = (size_t)((b0 + j) * 64 + o) * 518 + p;
    am[off] = accA[j];
    dm[off] = accD[j];
  }
}

// ---------------- Fused synthesis: idwt level4->r3, then level3 -> recon2 (bf16)
__global__ __launch_bounds__(256) void k_syn32(const float* __restrict__ a4m,
                                               const float* __restrict__ d4m,
                                               const float* __restrict__ d3,
                                               __hip_bfloat16* __restrict__ r2out) {
  const int r = blockIdx.x;
  const int tid = threadIdx.x;
  __shared__ float sa[518], sd[518], s3d[1030], r3[1030];
  for (int i = tid; i < 518; i += 256) {
    sa[i] = a4m[(size_t)r * 518 + i];
    sd[i] = d4m[(size_t)r * 518 + i];
  }
  for (int i = tid; i < 1030; i += 256) s3d[i] = d3[(size_t)r * 1030 + i];
  __syncthreads();
  for (int s = tid; s < 1030; s += 256) {
    int u = s >> 1, par = s & 1;
    float acc = 0.f;
#pragma unroll
    for (int t = 0; t < 4; ++t) {
      int i = u + 3 - t;
      float fl = par ? c_RL[2 * t + 1] : c_RL[2 * t];
      float fh = par ? c_RH[2 * t + 1] : c_RH[2 * t];
      acc += fl * sa[i] + fh * sd[i];
    }
    r3[s] = acc;
  }
  __syncthreads();
  for (int s = tid; s < 2053; s += 256) {
    int u = s >> 1, par = s & 1;
    float acc = 0.f;
#pragma unroll
    for (int t = 0; t < 4; ++t) {
      int i = u + 3 - t;
      float fl = par ? c_RL[2 * t + 1] : c_RL[2 * t];
      float fh = par ? c_RH[2 * t + 1] : c_RH[2 * t];
      acc += fl * r3[i] + fh * s3d[i];
    }
    r2out[(size_t)r * S2R + s] = __float2bfloat16(acc);
  }
}

// ---------------- Generic IDWT level with strides (used for level 2 -> recon1)
template <typename TCa, typename TCd, typename TOut>
__global__ void k_idwt(const TCa* __restrict__ ca, const TCd* __restrict__ cd,
                       TOut* __restrict__ out, int m, int out_len, int sin, int sout) {
  int s = blockIdx.x * blockDim.x + threadIdx.x;
  if (s >= out_len) return;
  const TCa* pa = ca + (size_t)blockIdx.y * sin;
  const TCd* pd = cd + (size_t)blockIdx.y * sin;
  int u = s >> 1, par = s & 1;
  float acc = 0.f;
#pragma unroll
  for (int t = 0; t < 4; ++t) {
    int i = u + 3 - t;
    float fl = par ? c_RL[2 * t + 1] : c_RL[2 * t];
    float fh = par ? c_RH[2 * t + 1] : c_RH[2 * t];
    acc += fl * ldf(pa, i) + fh * ldf(pd, i);
  }
  stf(out, (size_t)blockIdx.y * sout + s, acc);
}

// ---------------- Epilogue: MFMA dense shortcut + final IDWT + bias + mish -> fp32
// block 256 (4 waves), tile 64n x 64o, grid (128, 32)
__global__ __launch_bounds__(256) void k_epilogue(const __hip_bfloat16* __restrict__ r1,
                                                  const __hip_bfloat16* __restrict__ dd1,
                                                  const float* __restrict__ x,
                                                  const float* __restrict__ dk,
                                                  const float* __restrict__ bias,
                                                  float* __restrict__ out) {
  const int b = blockIdx.y;
  const int n0 = blockIdx.x * 64;
  const int u0 = n0 >> 1;
  const int tid = threadIdx.x;
  const int lane = tid & 63;
  const int w = tid >> 6;

  __shared__ __hip_bfloat16 Kt[64 * 72];  // Kt[o][c], row pad to 72 (144B, 16B-aligned rows)
  __shared__ float ra[35 * 65];
  __shared__ float rd[35 * 65];

  // stage Kt = K^T (bf16)
  {
    const float4* dk4 = (const float4*)dk;
    for (int idx = tid; idx < 1024; idx += 256) {
      int c = idx >> 4, o0 = (idx & 15) * 4;
      float4 v = dk4[idx];  // dk[c][o0..o0+3]
      Kt[(o0 + 0) * 72 + c] = __float2bfloat16(v.x);
      Kt[(o0 + 1) * 72 + c] = __float2bfloat16(v.y);
      Kt[(o0 + 2) * 72 + c] = __float2bfloat16(v.z);
      Kt[(o0 + 3) * 72 + c] = __float2bfloat16(v.w);
    }
  }
  // stage ra/rd (35 coeffs x 64 channels)
  {
    int o2 = tid >> 2;
    const __hip_bfloat16* pr = r1 + (size_t)(b * 64 + o2) * S1R + u0;
    const __hip_bfloat16* pd = dd1 + (size_t)(b * 64 + o2) * S1R + u0;
    for (int il = (tid & 3); il < 35; il += 4) {
      ra[il * 65 + o2] = __bfloat162float(pr[il]);
      rd[il * 65 + o2] = __bfloat162float(pd[il]);
    }
  }
  __syncthreads();

  const int m16 = lane & 15;        // A-row within 16-tile / B-col within o-tile
  const int kq = (lane >> 4) * 8;   // k sub-offset
  const int nrow = w * 16 + m16;    // this lane's A row (n_loc) for loading
  const float* xrow = x + ((size_t)b * 8192 + n0 + nrow) * 64;

  floatx4 acc[4];
#pragma unroll
  for (int ot = 0; ot < 4; ++ot) acc[ot] = (floatx4){0.f, 0.f, 0.f, 0.f};

#pragma unroll
  for (int ks = 0; ks < 2; ++ks) {
    float4 xa = *(const float4*)(xrow + ks * 32 + kq);
    float4 xb = *(const float4*)(xrow + ks * 32 + kq + 4);
    short8 af;
    af[0] = f2bs(xa.x); af[1] = f2bs(xa.y); af[2] = f2bs(xa.z); af[3] = f2bs(xa.w);
    af[4] = f2bs(xb.x); af[5] = f2bs(xb.y); af[6] = f2bs(xb.z); af[7] = f2bs(xb.w);
#pragma unroll
    for (int ot = 0; ot < 4; ++ot) {
      short8 bf = *(const short8*)&Kt[(ot * 16 + m16) * 72 + ks * 32 + kq];
      acc[ot] = __builtin_amdgcn_mfma_f32_16x16x32_bf16(af, bf, acc[ot], 0, 0, 0);
    }
  }

  // epilogue: C/D layout col=lane&15 (o), row=(lane>>4)*4+reg (n)
  const int rbase = (lane >> 4) * 4;
#pragma unroll
  for (int ot = 0; ot < 4; ++ot) {
    int o_loc = ot * 16 + m16;
    float bo = bias[o_loc];
#pragma unroll
    for (int rg = 0; rg < 4; ++rg) {
      int n_loc = w * 16 + rbase + rg;
      int ul = n_loc >> 1, par = n_loc & 1;
      float wv = 0.f;
#pragma unroll
      for (int t = 0; t < 4; ++t) {
        int i = ul + 3 - t;
        float fl = par ? c_RL[2 * t + 1] : c_RL[2 * t];
        float fh = par ? c_RH[2 * t + 1] : c_RH[2 * t];
        wv += fl * ra[i * 65 + o_loc] + fh * rd[i * 65 + o_loc];
      }
      float v = acc[ot][rg] + wv + bo;
      float e = __expf(fminf(v, 15.f));
      float num = e * (e + 2.f);
      float mm = (v > 15.f) ? v : v * (num / (num + 2.f));
      out[((size_t)b * 8192 + n0 + n_loc) * 64 + o_loc] = mm;
    }
  }
}

// ---------------- host ----------------
extern "C" void kernel_launch(void* const* d_in, const int* in_sizes, int n_in,
                              void* d_out, int out_size, void* d_ws, size_t ws_size,
                              hipStream_t stream) {
  const float* x    = (const float*)d_in[0];
  const float* w1   = (const float*)d_in[1];
  const float* w2   = (const float*)d_in[2];
  const float* dk   = (const float*)d_in[3];
  const float* bias = (const float*)d_in[4];
  float* out = (float*)d_out;

  const size_t R = 2048;

  float* wf = (float*)d_ws;
  float* d3f = wf; wf += R * 1030;
  float* a4f = wf; wf += R * 518;
  float* d4f = wf; wf += R * 518;
  float* a4m = wf; wf += R * 518;
  float* d4m = wf; wf += R * 518;
  __hip_bfloat16* wb = (__hip_bfloat16*)wf;
  __hip_bfloat16* a1b = wb; wb += R * S1R;  // analysis a1, later recon1
  __hip_bfloat16* d1b = wb; wb += R * S1R;
  __hip_bfloat16* a2b = wb; wb += R * S2R;  // analysis a2 unused; holds recon2
  __hip_bfloat16* d2b = wb; wb += R * S2R;
  // total ~75.8 MB

  k_dwt_first<<<dim3(65, 32), 256, 0, stream>>>(x, a1b, d1b);
  k_ana234<<<dim3(2048), 256, 0, stream>>>(a1b, d2b, d3f, a4f, d4f);
  k_mix<<<dim3(130, 4), 256, 0, stream>>>(a4f, d4f, w1, w2, a4m, d4m);
  k_syn32<<<dim3(2048), 256, 0, stream>>>(a4m, d4m, d3f, a2b);
  k_idwt<__hip_bfloat16, __hip_bfloat16, __hip_bfloat16>
      <<<dim3((4099 + 255) / 256, 2048), 256, 0, stream>>>(a2b, d2b, a1b, 2053, 4099, S2R, S1R);
  k_epilogue<<<dim3(128, 32), 256, 0, stream>>>(a1b, d1b, x, dk, bias, out);
}

// Round 6
// 298.776 us; speedup vs baseline: 1.2129x; 1.2129x over previous
//
#include <hip/hip_runtime.h>
#include <hip/hip_bf16.h>
#include <stdint.h>

typedef __attribute__((ext_vector_type(8))) short short8;
typedef __attribute__((ext_vector_type(4))) float floatx4;

// ---------------- db4 filter constants ----------------
__device__ __constant__ float c_DL[8] = {
    -0.010597401784997278f, 0.032883011666982945f, 0.030841381835986965f,
    -0.18703481171888114f, -0.02798376941698385f, 0.6308807679295904f,
    0.7148465705525415f, 0.23037781330885523f};
__device__ __constant__ float c_DH[8] = {
    -0.23037781330885523f, 0.7148465705525415f, -0.6308807679295904f,
    -0.02798376941698385f, 0.18703481171888114f, 0.030841381835986965f,
    -0.032883011666982945f, -0.010597401784997278f};
// REC_LO = reverse(DEC_LO) (also used as reversed-order analysis lowpass)
__device__ __constant__ float c_RL[8] = {
    0.23037781330885523f, 0.7148465705525415f, 0.6308807679295904f,
    -0.02798376941698385f, -0.18703481171888114f, 0.030841381835986965f,
    0.032883011666982945f, -0.010597401784997278f};
__device__ __constant__ float c_RH[8] = {
    -0.010597401784997278f, -0.032883011666982945f, 0.030841381835986965f,
    0.18703481171888114f, -0.02798376941698385f, -0.6308807679295904f,
    0.7148465705525415f, -0.23037781330885523f};

__device__ __forceinline__ float bflo(uint32_t u) { return __uint_as_float(u << 16); }
__device__ __forceinline__ float bfhi(uint32_t u) { return __uint_as_float(u & 0xffff0000u); }
__device__ __forceinline__ float ldf(const float* p, size_t i) { return p[i]; }
__device__ __forceinline__ float ldf(const __hip_bfloat16* p, size_t i) { return __bfloat162float(p[i]); }
__device__ __forceinline__ void stf(float* p, size_t i, float v) { p[i] = v; }
__device__ __forceinline__ void stf(__hip_bfloat16* p, size_t i, float v) { p[i] = __float2bfloat16(v); }
__device__ __forceinline__ short f2bs(float f) {
  __hip_bfloat16 h = __float2bfloat16(f);
  return *reinterpret_cast<short*>(&h);
}

__device__ __forceinline__ int reflect_idx(int t, int n) {
  if (t < 0) t = -1 - t;
  if (t >= n) t = 2 * n - 1 - t;
  return t;
}

// Row strides (padded for aligned vector access)
#define S1R 4100
#define S2R 2056

// ---------------- Level-1 DWT: x (B,N,C) fp32, transposed read -> a1,d1 (B*C, stride 4100) bf16
#define NT1 134
__global__ __launch_bounds__(256) void k_dwt_first(const float* __restrict__ x,
                                                   __hip_bfloat16* __restrict__ outa,
                                                   __hip_bfloat16* __restrict__ outd) {
  const int b = blockIdx.y;
  const int k0 = blockIdx.x * 64;
  const int tid = threadIdx.x;
  __shared__ float xs[NT1 * 65];

  const float4* x4 = (const float4*)x;
  for (int idx = tid; idx < NT1 * 16; idx += 256) {
    int nl = idx >> 4, cq = idx & 15;
    int t = 2 * k0 - 6 + nl;
    int n = reflect_idx(t, 8192);
    float4 v = x4[((size_t)b * 8192 + n) * 16 + cq];
    float* d = &xs[nl * 65 + 4 * cq];
    d[0] = v.x; d[1] = v.y; d[2] = v.z; d[3] = v.w;
  }
  __syncthreads();

  const int kk = tid & 63;
  const int k = k0 + kk;
  if (k >= 4099) return;
  for (int c = (tid >> 6); c < 64; c += 4) {
    float lo = 0.f, hi = 0.f;
#pragma unroll
    for (int j = 0; j < 8; ++j) {
      float v = xs[(2 * kk + 7 - j) * 65 + c];
      lo += c_DL[j] * v;
      hi += c_DH[j] * v;
    }
    size_t s = (size_t)b * 64 + c;
    outa[s * S1R + k] = __float2bfloat16(lo);
    outd[s * S1R + k] = __float2bfloat16(hi);
  }
}

// ---------------- Fused analysis levels 2..4, one row per block
__global__ __launch_bounds__(256) void k_ana234(const __hip_bfloat16* __restrict__ a1,
                                                __hip_bfloat16* __restrict__ d2o,
                                                float* __restrict__ d3o,
                                                float* __restrict__ a4o,
                                                float* __restrict__ d4o) {
  const int r = blockIdx.x;
  const int tid = threadIdx.x;
  __shared__ float s1[4100];
  __shared__ float s2[2054];
  __shared__ float s3[1032];

  const uint2* row2 = (const uint2*)(a1 + (size_t)r * S1R);
  for (int i = tid; i < 1025; i += 256) {
    uint2 u = row2[i];
    int e = 4 * i;
    s1[e] = bflo(u.x); s1[e + 1] = bfhi(u.x);
    s1[e + 2] = bflo(u.y); s1[e + 3] = bfhi(u.y);
  }
  __syncthreads();

  // level 2: n=4099 -> m=2053
  for (int k = tid; k < 2053; k += 256) {
    float lo = 0.f, hi = 0.f;
    if (k >= 3 && k <= 2048) {
      const float2* p = (const float2*)&s1[2 * k - 6];
      float2 v0 = p[0], v1 = p[1], v2 = p[2], v3 = p[3];
      lo = c_RL[0]*v0.x + c_RL[1]*v0.y + c_RL[2]*v1.x + c_RL[3]*v1.y +
           c_RL[4]*v2.x + c_RL[5]*v2.y + c_RL[6]*v3.x + c_RL[7]*v3.y;
      hi = c_RH[0]*v0.x + c_RH[1]*v0.y + c_RH[2]*v1.x + c_RH[3]*v1.y +
           c_RH[4]*v2.x + c_RH[5]*v2.y + c_RH[6]*v3.x + c_RH[7]*v3.y;
    } else {
#pragma unroll
      for (int j = 0; j < 8; ++j) {
        float v = s1[reflect_idx(2 * k + 1 - j, 4099)];
        lo += c_DL[j] * v; hi += c_DH[j] * v;
      }
    }
    d2o[(size_t)r * S2R + k] = __float2bfloat16(hi);
    s2[k] = lo;
  }
  __syncthreads();

  // level 3: n=2053 -> m=1030
  for (int k = tid; k < 1030; k += 256) {
    float lo = 0.f, hi = 0.f;
    if (k >= 3 && k <= 1025) {
      const float2* p = (const float2*)&s2[2 * k - 6];
      float2 v0 = p[0], v1 = p[1], v2 = p[2], v3 = p[3];
      lo = c_RL[0]*v0.x + c_RL[1]*v0.y + c_RL[2]*v1.x + c_RL[3]*v1.y +
           c_RL[4]*v2.x + c_RL[5]*v2.y + c_RL[6]*v3.x + c_RL[7]*v3.y;
      hi = c_RH[0]*v0.x + c_RH[1]*v0.y + c_RH[2]*v1.x + c_RH[3]*v1.y +
           c_RH[4]*v2.x + c_RH[5]*v2.y + c_RH[6]*v3.x + c_RH[7]*v3.y;
    } else {
#pragma unroll
      for (int j = 0; j < 8; ++j) {
        float v = s2[reflect_idx(2 * k + 1 - j, 2053)];
        lo += c_DL[j] * v; hi += c_DH[j] * v;
      }
    }
    d3o[(size_t)r * 1030 + k] = hi;
    s3[k] = lo;
  }
  __syncthreads();

  // level 4: n=1030 -> m=518
  for (int k = tid; k < 518; k += 256) {
    float lo = 0.f, hi = 0.f;
    if (k >= 3 && k <= 514) {
      const float2* p = (const float2*)&s3[2 * k - 6];
      float2 v0 = p[0], v1 = p[1], v2 = p[2], v3 = p[3];
      lo = c_RL[0]*v0.x + c_RL[1]*v0.y + c_RL[2]*v1.x + c_RL[3]*v1.y +
           c_RL[4]*v2.x + c_RL[5]*v2.y + c_RL[6]*v3.x + c_RL[7]*v3.y;
      hi = c_RH[0]*v0.x + c_RH[1]*v0.y + c_RH[2]*v1.x + c_RH[3]*v1.y +
           c_RH[4]*v2.x + c_RH[5]*v2.y + c_RH[6]*v3.x + c_RH[7]*v3.y;
    } else {
#pragma unroll
      for (int j = 0; j < 8; ++j) {
        float v = s3[reflect_idx(2 * k + 1 - j, 1030)];
        lo += c_DL[j] * v; hi += c_DH[j] * v;
      }
    }
    a4o[(size_t)r * 518 + k] = lo;
    d4o[(size_t)r * 518 + k] = hi;
  }
}

// ---------------- Channel mixing v3: batch-fastest dispatch for L2 w-reuse
// grid (16, 130): blockIdx.x = batch-pair (b0 = 2*bx), blockIdx.y = (o,p)-chunk of 256.
// The 16 x-blocks of one chunk launch consecutively and share the same 131 KB w slice in L2.
__global__ __launch_bounds__(256) void k_mix(const float* __restrict__ a4,
                                             const float* __restrict__ d4,
                                             const float* __restrict__ w1,
                                             const float* __restrict__ w2,
                                             float* __restrict__ am,
                                             float* __restrict__ dm) {
  int idx = blockIdx.y * 256 + threadIdx.x;
  if (idx >= 64 * 518) return;
  int o = idx / 518;
  int p = idx - o * 518;
  int b0 = blockIdx.x * 2;

  float a0 = 0.f, a1 = 0.f, dd0 = 0.f, dd1 = 0.f;

  const float* w1p = w1 + (size_t)o * 518 + p;        // + i*64*518
  const float* w2p = w2 + (size_t)o * 518 + p;
  const float* a4p = a4 + (size_t)b0 * 64 * 518 + p;  // + (j*64+i)*518
  const float* d4p = d4 + (size_t)b0 * 64 * 518 + p;

  for (int i = 0; i < 64; ++i) {
    float wa = w1p[(size_t)i * (64 * 518)];
    float wd = w2p[(size_t)i * (64 * 518)];
    size_t o0 = (size_t)i * 518;
    size_t o1 = (size_t)(64 + i) * 518;
    a0  += a4p[o0] * wa;
    a1  += a4p[o1] * wa;
    dd0 += d4p[o0] * wd;
    dd1 += d4p[o1] * wd;
  }
  size_t s0 = (size_t)(b0 * 64 + o) * 518 + p;
  size_t s1 = (size_t)((b0 + 1) * 64 + o) * 518 + p;
  am[s0] = a0;  am[s1] = a1;
  dm[s0] = dd0; dm[s1] = dd1;
}

// ---------------- Fused synthesis: idwt level4->r3, then level3 -> recon2 (bf16)
__global__ __launch_bounds__(256) void k_syn32(const float* __restrict__ a4m,
                                               const float* __restrict__ d4m,
                                               const float* __restrict__ d3,
                                               __hip_bfloat16* __restrict__ r2out) {
  const int r = blockIdx.x;
  const int tid = threadIdx.x;
  __shared__ float sa[518], sd[518], s3d[1030], r3[1030];
  for (int i = tid; i < 518; i += 256) {
    sa[i] = a4m[(size_t)r * 518 + i];
    sd[i] = d4m[(size_t)r * 518 + i];
  }
  for (int i = tid; i < 1030; i += 256) s3d[i] = d3[(size_t)r * 1030 + i];
  __syncthreads();
  for (int s = tid; s < 1030; s += 256) {
    int u = s >> 1, par = s & 1;
    float acc = 0.f;
#pragma unroll
    for (int t = 0; t < 4; ++t) {
      int i = u + 3 - t;
      float fl = par ? c_RL[2 * t + 1] : c_RL[2 * t];
      float fh = par ? c_RH[2 * t + 1] : c_RH[2 * t];
      acc += fl * sa[i] + fh * sd[i];
    }
    r3[s] = acc;
  }
  __syncthreads();
  for (int s = tid; s < 2053; s += 256) {
    int u = s >> 1, par = s & 1;
    float acc = 0.f;
#pragma unroll
    for (int t = 0; t < 4; ++t) {
      int i = u + 3 - t;
      float fl = par ? c_RL[2 * t + 1] : c_RL[2 * t];
      float fh = par ? c_RH[2 * t + 1] : c_RH[2 * t];
      acc += fl * r3[i] + fh * s3d[i];
    }
    r2out[(size_t)r * S2R + s] = __float2bfloat16(acc);
  }
}

// ---------------- Generic IDWT level with strides (used for level 2 -> recon1)
template <typename TCa, typename TCd, typename TOut>
__global__ void k_idwt(const TCa* __restrict__ ca, const TCd* __restrict__ cd,
                       TOut* __restrict__ out, int m, int out_len, int sin, int sout) {
  int s = blockIdx.x * blockDim.x + threadIdx.x;
  if (s >= out_len) return;
  const TCa* pa = ca + (size_t)blockIdx.y * sin;
  const TCd* pd = cd + (size_t)blockIdx.y * sin;
  int u = s >> 1, par = s & 1;
  float acc = 0.f;
#pragma unroll
  for (int t = 0; t < 4; ++t) {
    int i = u + 3 - t;
    float fl = par ? c_RL[2 * t + 1] : c_RL[2 * t];
    float fh = par ? c_RH[2 * t + 1] : c_RH[2 * t];
    acc += fl * ldf(pa, i) + fh * ldf(pd, i);
  }
  stf(out, (size_t)blockIdx.y * sout + s, acc);
}

// ---------------- Epilogue: MFMA dense shortcut + final IDWT + bias + mish -> fp32
// block 256 (4 waves), tile 64n x 64o, grid (128, 32)
__global__ __launch_bounds__(256) void k_epilogue(const __hip_bfloat16* __restrict__ r1,
                                                  const __hip_bfloat16* __restrict__ dd1,
                                                  const float* __restrict__ x,
                                                  const float* __restrict__ dk,
                                                  const float* __restrict__ bias,
                                                  float* __restrict__ out) {
  const int b = blockIdx.y;
  const int n0 = blockIdx.x * 64;
  const int u0 = n0 >> 1;
  const int tid = threadIdx.x;
  const int lane = tid & 63;
  const int w = tid >> 6;

  __shared__ __hip_bfloat16 Kt[64 * 72];  // Kt[o][c], row pad to 72 (144B, 16B-aligned rows)
  __shared__ float ra[35 * 65];
  __shared__ float rd[35 * 65];

  // stage Kt = K^T (bf16)
  {
    const float4* dk4 = (const float4*)dk;
    for (int idx = tid; idx < 1024; idx += 256) {
      int c = idx >> 4, o0 = (idx & 15) * 4;
      float4 v = dk4[idx];  // dk[c][o0..o0+3]
      Kt[(o0 + 0) * 72 + c] = __float2bfloat16(v.x);
      Kt[(o0 + 1) * 72 + c] = __float2bfloat16(v.y);
      Kt[(o0 + 2) * 72 + c] = __float2bfloat16(v.z);
      Kt[(o0 + 3) * 72 + c] = __float2bfloat16(v.w);
    }
  }
  // stage ra/rd (35 coeffs x 64 channels)
  {
    int o2 = tid >> 2;
    const __hip_bfloat16* pr = r1 + (size_t)(b * 64 + o2) * S1R + u0;
    const __hip_bfloat16* pd = dd1 + (size_t)(b * 64 + o2) * S1R + u0;
    for (int il = (tid & 3); il < 35; il += 4) {
      ra[il * 65 + o2] = __bfloat162float(pr[il]);
      rd[il * 65 + o2] = __bfloat162float(pd[il]);
    }
  }
  __syncthreads();

  const int m16 = lane & 15;        // A-row within 16-tile / B-col within o-tile
  const int kq = (lane >> 4) * 8;   // k sub-offset
  const int nrow = w * 16 + m16;    // this lane's A row (n_loc) for loading
  const float* xrow = x + ((size_t)b * 8192 + n0 + nrow) * 64;

  floatx4 acc[4];
#pragma unroll
  for (int ot = 0; ot < 4; ++ot) acc[ot] = (floatx4){0.f, 0.f, 0.f, 0.f};

#pragma unroll
  for (int ks = 0; ks < 2; ++ks) {
    float4 xa = *(const float4*)(xrow + ks * 32 + kq);
    float4 xb = *(const float4*)(xrow + ks * 32 + kq + 4);
    short8 af;
    af[0] = f2bs(xa.x); af[1] = f2bs(xa.y); af[2] = f2bs(xa.z); af[3] = f2bs(xa.w);
    af[4] = f2bs(xb.x); af[5] = f2bs(xb.y); af[6] = f2bs(xb.z); af[7] = f2bs(xb.w);
#pragma unroll
    for (int ot = 0; ot < 4; ++ot) {
      short8 bf = *(const short8*)&Kt[(ot * 16 + m16) * 72 + ks * 32 + kq];
      acc[ot] = __builtin_amdgcn_mfma_f32_16x16x32_bf16(af, bf, acc[ot], 0, 0, 0);
    }
  }

  // epilogue: C/D layout col=lane&15 (o), row=(lane>>4)*4+reg (n)
  const int rbase = (lane >> 4) * 4;
#pragma unroll
  for (int ot = 0; ot < 4; ++ot) {
    int o_loc = ot * 16 + m16;
    float bo = bias[o_loc];
#pragma unroll
    for (int rg = 0; rg < 4; ++rg) {
      int n_loc = w * 16 + rbase + rg;
      int ul = n_loc >> 1, par = n_loc & 1;
      float wv = 0.f;
#pragma unroll
      for (int t = 0; t < 4; ++t) {
        int i = ul + 3 - t;
        float fl = par ? c_RL[2 * t + 1] : c_RL[2 * t];
        float fh = par ? c_RH[2 * t + 1] : c_RH[2 * t];
        wv += fl * ra[i * 65 + o_loc] + fh * rd[i * 65 + o_loc];
      }
      float v = acc[ot][rg] + wv + bo;
      float e = __expf(fminf(v, 15.f));
      float num = e * (e + 2.f);
      float mm = (v > 15.f) ? v : v * (num / (num + 2.f));
      out[((size_t)b * 8192 + n0 + n_loc) * 64 + o_loc] = mm;
    }
  }
}

// ---------------- host ----------------
extern "C" void kernel_launch(void* const* d_in, const int* in_sizes, int n_in,
                              void* d_out, int out_size, void* d_ws, size_t ws_size,
                              hipStream_t stream) {
  const float* x    = (const float*)d_in[0];
  const float* w1   = (const float*)d_in[1];
  const float* w2   = (const float*)d_in[2];
  const float* dk   = (const float*)d_in[3];
  const float* bias = (const float*)d_in[4];
  float* out = (float*)d_out;

  const size_t R = 2048;

  float* wf = (float*)d_ws;
  float* d3f = wf; wf += R * 1030;
  float* a4f = wf; wf += R * 518;
  float* d4f = wf; wf += R * 518;
  float* a4m = wf; wf += R * 518;
  float* d4m = wf; wf += R * 518;
  __hip_bfloat16* wb = (__hip_bfloat16*)wf;
  __hip_bfloat16* a1b = wb; wb += R * S1R;  // analysis a1, later recon1
  __hip_bfloat16* d1b = wb; wb += R * S1R;
  __hip_bfloat16* a2b = wb; wb += R * S2R;  // analysis a2 unused; holds recon2
  __hip_bfloat16* d2b = wb; wb += R * S2R;
  // total ~75.8 MB

  k_dwt_first<<<dim3(65, 32), 256, 0, stream>>>(x, a1b, d1b);
  k_ana234<<<dim3(2048), 256, 0, stream>>>(a1b, d2b, d3f, a4f, d4f);
  // batch-fastest grid: 16 batch-pairs x 130 chunks
  k_mix<<<dim3(16, 130), 256, 0, stream>>>(a4f, d4f, w1, w2, a4m, d4m);
  k_syn32<<<dim3(2048), 256, 0, stream>>>(a4m, d4m, d3f, a2b);
  k_idwt<__hip_bfloat16, __hip_bfloat16, __hip_bfloat16>
      <<<dim3((4099 + 255) / 256, 2048), 256, 0, stream>>>(a2b, d2b, a1b, 2053, 4099, S2R, S1R);
  k_epilogue<<<dim3(128, 32), 256, 0, stream>>>(a1b, d1b, x, dk, bias, out);
}